// Round 6
// baseline (278.936 us; speedup 1.0000x reference)
//
#include <hip/hip_runtime.h>
#include <hip/hip_bf16.h>

// Attention_44006234915573 — windowed attention, MI355X/gfx950
// B=256, D=128, HEADS=4, DH=32, N=625 (padded to 640).
//
// R6: transpose split out of the QKV GEMM.
//  - k_xpose: x f32 [b][128][625] -> xT bf16 [b][640][128] (LDS 64x128 tile)
//  - k_qkv: LDS-free, barrier-free; A-frags = b128 loads from xT; W in regs;
//    3 col-frags/wave, 2 column-flavors per (b,tile) -> 5120 blocks, ~95 VGPR.
//  - k_attn (swapped 32x32 MFMA, in-register softmax) unchanged from R4.
//
// ws layout (bytes):
//   [0,          +40M)  Q  bf16 [1024][640][32] (pre-scaled by SCALE*LOG2E)
//   [41943040,   +40M)  K  bf16 [1024][640][32]
//   [83886080,   +40M)  Vt bf16 [1024][32][640]
//   [125829120,  +40M)  O  bf16 [256][640][128] (head-major channels)
//   [167772160, +3.3M)  bias bf16 [4][160 jg][640 i][4]  (pre-x LOG2E)
//   [171048960, +96K)   W_qkv bf16 [384][128]
//   [171147264, +32K)   W_out bf16 [128][128]
//   [171180032, +20.9M) xT bf16 [256][640][128]
// total 192,152,072 bytes of d_ws.

typedef __attribute__((ext_vector_type(8)))  short short8;
typedef __attribute__((ext_vector_type(4)))  float f32x4;
typedef __attribute__((ext_vector_type(16))) float f32x16;

#define MFMA16(a, b, c) __builtin_amdgcn_mfma_f32_16x16x32_bf16((a), (b), (c), 0, 0, 0)
#define MFMA32(a, b, c) __builtin_amdgcn_mfma_f32_32x32x16_bf16((a), (b), (c), 0, 0, 0)

__device__ __forceinline__ unsigned short f2b(float f) {
  __hip_bfloat16 h = __float2bfloat16(f);
  return *reinterpret_cast<unsigned short*>(&h);
}
__device__ __forceinline__ float b2f(unsigned short s) {
  union { unsigned u; float f; } x; x.u = ((unsigned)s) << 16;
  return x.f;
}
__device__ __forceinline__ unsigned cvtpk(float lo, float hi) {
  unsigned r;
  asm("v_cvt_pk_bf16_f32 %0, %1, %2" : "=v"(r) : "v"(lo), "v"(hi));
  return r;
}
__device__ __forceinline__ void pl32swap(unsigned& a, unsigned& b) {
  asm("v_permlane32_swap_b32 %0, %1" : "+v"(a), "+v"(b));
}

constexpr float LOG2E_F = 1.4426950408889634f;
constexpr float QSCALE  = 0.17677669529663687f * 1.4426950408889634f;  // dh^-0.5 * log2(e)

// ---------------------------------------------------------------- weight cvt
__global__ __launch_bounds__(256) void k_prep(const float* __restrict__ wqkv,
                                              const float* __restrict__ wout,
                                              unsigned short* __restrict__ wq_bf,
                                              unsigned short* __restrict__ wo_bf) {
  int id = blockIdx.x * 256 + threadIdx.x;   // 65536 = 49152 + 16384
  if (id < 49152) wq_bf[id] = f2b(wqkv[id]);
  else            wo_bf[id - 49152] = f2b(wout[id - 49152]);
}

// ---------------------------------------------------------------- x transpose
// x [b][128 d][625 n] f32 -> xT [b][640 n][128 d] bf16 (rows >=625 zeroed)
__global__ __launch_bounds__(256) void k_xpose(const float* __restrict__ x,
                                               unsigned short* __restrict__ xt) {
  __shared__ unsigned short Xl[128 * 65];    // 16.6 KB
  int blk = blockIdx.x;                      // 2560 = 256 b x 10 tile
  int b = blk / 10, tile = blk % 10;
  int n0 = tile * 64, t = threadIdx.x;
  const float* xb = x + (size_t)b * 80000;
  for (int it = 0; it < 32; ++it) {
    int idx = it * 256 + t;                  // 8192 = 128 d x 64 n
    int d = idx >> 6, nc = idx & 63, n = n0 + nc;
    Xl[d * 65 + nc] = (n < 625) ? f2b(xb[d * 625 + n]) : (unsigned short)0;
  }
  __syncthreads();
  unsigned short* xtb = xt + ((size_t)b * 640 + n0) * 128;
  for (int it = 0; it < 4; ++it) {
    int idx = it * 256 + t;                  // 1024 short8 chunks
    int row = idx >> 4, c8 = (idx & 15) * 8;
    short8 v;
#pragma unroll
    for (int jj = 0; jj < 8; ++jj) v[jj] = (short)Xl[(c8 + jj) * 65 + row];
    *reinterpret_cast<short8*>(xtb + row * 128 + c8) = v;
  }
}

// ---------------------------------------------------------------- bias expand
// output: bt[h][jg][i][e] = LOG2E * table[idx[i][4jg+e]][h]; j>=625 -> -1e30,
// (j<625, i>=625) -> 0. Coalesced ushort4 writes; lane-consecutive i on read.
__global__ __launch_bounds__(256) void k_bias(const float* __restrict__ table,
                                              const int* __restrict__ idx,
                                              unsigned short* __restrict__ bt) {
  int id = blockIdx.x * 256 + threadIdx.x;   // 102400 over (jg, i)
  int jg = id / 640, i = id % 640;
  float v[4][4];                              // [e][h]
#pragma unroll
  for (int e = 0; e < 4; ++e) {
    int j = jg * 4 + e;
    if (j >= 625) {
#pragma unroll
      for (int h = 0; h < 4; ++h) v[e][h] = -1e30f;
    } else if (i >= 625) {
#pragma unroll
      for (int h = 0; h < 4; ++h) v[e][h] = 0.f;
    } else {
      const float* tr = table + idx[i * 625 + j] * 4;
#pragma unroll
      for (int h = 0; h < 4; ++h) v[e][h] = tr[h] * LOG2E_F;
    }
  }
#pragma unroll
  for (int h = 0; h < 4; ++h) {
    ushort4 p;
    p.x = f2b(v[0][h]); p.y = f2b(v[1][h]); p.z = f2b(v[2][h]); p.w = f2b(v[3][h]);
    *reinterpret_cast<ushort4*>(bt + (size_t)h * 409600 + (size_t)id * 4) = p;
  }
}

// ---------------------------------------------------------------- QKV proj
// LDS-free: one block per (b, 64-row tile, col-flavor); wave w owns 3 col
// fragments F0..F0+2; W in registers; A-frags = b128 loads from xT.
__global__ __launch_bounds__(256) void k_qkv(const unsigned short* __restrict__ xt,
                                             const unsigned short* __restrict__ wbf,
                                             unsigned short* __restrict__ qws,
                                             unsigned short* __restrict__ kws,
                                             unsigned short* __restrict__ vtws) {
  int blk = blockIdx.x;                      // 5120 = 256 b x 10 tile x 2 cf
  int cf = blk & 1, btl = blk >> 1;
  int b = btl / 10, tile = btl % 10;
  int t = threadIdx.x, w = t >> 6, lane = t & 63, r16 = lane & 15, g = lane >> 4;
  int F0 = cf * 12 + w * 3;
  short8 wf[3][4];
#pragma unroll
  for (int f = 0; f < 3; ++f)
#pragma unroll
    for (int kk = 0; kk < 4; ++kk)
      wf[f][kk] = *reinterpret_cast<const short8*>(
          wbf + ((F0 + f) * 16 + r16) * 128 + kk * 32 + g * 8);
  const unsigned short* xb = xt + ((size_t)b * 640 + tile * 64) * 128;
#pragma unroll
  for (int rg = 0; rg < 4; ++rg) {
    short8 a[4];
#pragma unroll
    for (int kk = 0; kk < 4; ++kk)
      a[kk] = *reinterpret_cast<const short8*>(xb + (rg * 16 + r16) * 128 + kk * 32 + g * 8);
    f32x4 acc[3];
#pragma unroll
    for (int f = 0; f < 3; ++f) acc[f] = (f32x4){0.f, 0.f, 0.f, 0.f};
#pragma unroll
    for (int kk = 0; kk < 4; ++kk)
#pragma unroll
      for (int f = 0; f < 3; ++f)
        acc[f] = MFMA16(a[kk], wf[f][kk], acc[f]);
    int nr = tile * 64 + rg * 16;
#pragma unroll
    for (int f = 0; f < 3; ++f) {
      int c0 = (F0 + f) * 16;
      int sel = c0 >> 7, hh = (c0 & 127) >> 5, t0 = (c0 & 31);
      float mul = (sel == 0) ? QSCALE : 1.f;
      size_t base = (size_t)(b * 4 + hh);
      if (sel < 2) {
        unsigned short* dst = (sel ? kws : qws) + (base * 640 + nr + 4 * g) * 32 + t0 + r16;
#pragma unroll
        for (int rr = 0; rr < 4; ++rr) dst[rr * 32] = f2b(acc[f][rr] * mul);
      } else {
        ushort4 pv;
        pv.x = f2b(acc[f][0]); pv.y = f2b(acc[f][1]);
        pv.z = f2b(acc[f][2]); pv.w = f2b(acc[f][3]);
        *reinterpret_cast<ushort4*>(vtws + (base * 32 + t0 + r16) * 640 + nr + 4 * g) = pv;
      }
    }
  }
}

// ---------------------------------------------------------------- attention
// one block (512 thr, 8 waves) per (b,h); swapped 32x32 MFMA; P in registers.
__global__ __launch_bounds__(512) void k_attn(const unsigned short* __restrict__ qws,
                                              const unsigned short* __restrict__ kws,
                                              const unsigned short* __restrict__ vtws,
                                              const unsigned short* __restrict__ bt,
                                              unsigned short* __restrict__ ows) {
  __shared__ __align__(16) unsigned short Kl[640 * 40];   // 51.2 KB, pitch 80B
  __shared__ __align__(16) unsigned short Vl[32 * 648];   // 41.5 KB
  int bh = blockIdx.x, b = bh >> 2, h = bh & 3;
  int t = threadIdx.x, w = t >> 6, lane = t & 63;
  int i31 = lane & 31, hi = lane >> 5;
  const unsigned short* Kg = kws + (size_t)bh * 20480;
  const unsigned short* Vg = vtws + (size_t)bh * 20480;
  for (int it = 0; it < 5; ++it) {
    int idx = it * 512 + t;                  // 2560 8-elem blocks of K
    int row = idx >> 2, c8 = (idx & 3) * 8;
    *reinterpret_cast<short8*>(&Kl[row * 40 + c8]) =
        *reinterpret_cast<const short8*>(Kg + row * 32 + c8);
  }
  for (int it = 0; it < 5; ++it) {
    int idx = it * 512 + t;                  // 2560 8-elem blocks of V
    int d = idx / 80, nb = (idx % 80) * 8;
    *reinterpret_cast<short8*>(&Vl[d * 648 + nb]) =
        *reinterpret_cast<const short8*>(Vg + d * 640 + nb);
  }
  __syncthreads();
  const unsigned short* Qg = qws + (size_t)bh * 20480;
  const unsigned short* bth = bt + (size_t)h * 409600;
  short8 ones;
#pragma unroll
  for (int jj = 0; jj < 8; ++jj) ones[jj] = (short)0x3F80;  // bf16 1.0

  for (int ti = w; ti < 20; ti += 8) {       // wave's 32-row Q tiles
    int i = ti * 32 + i31;
    short8 qf0 = *reinterpret_cast<const short8*>(Qg + i * 32 + hi * 8);
    short8 qf1 = *reinterpret_cast<const short8*>(Qg + i * 32 + 16 + hi * 8);
    f32x16 oacc, sacc;
#pragma unroll
    for (int r = 0; r < 16; ++r) { oacc[r] = 0.f; sacc[r] = 0.f; }
    for (int c = 0; c < 5; ++c) {
      int j0 = c * 128;
      f32x16 s[4];
      // bias as C-operand: s[jt][4q+e] = bias^T[j0+32jt+8q+4hi+e][i]
#pragma unroll
      for (int jt = 0; jt < 4; ++jt) {
#pragma unroll
        for (int q = 0; q < 4; ++q) {
          int jg = (j0 >> 2) + jt * 8 + q * 2 + hi;
          ushort4 bv = *reinterpret_cast<const ushort4*>(bth + ((size_t)jg * 640 + i) * 4);
          s[jt][4 * q + 0] = b2f(bv.x);
          s[jt][4 * q + 1] = b2f(bv.y);
          s[jt][4 * q + 2] = b2f(bv.z);
          s[jt][4 * q + 3] = b2f(bv.w);
        }
      }
      // S^T = K Q^T + bias  (32x32 j-tiles, k = dh = 32 in two halves)
#pragma unroll
      for (int jt = 0; jt < 4; ++jt) {
        const unsigned short* kr = &Kl[(j0 + jt * 32 + i31) * 40 + hi * 8];
        short8 kf0 = *reinterpret_cast<const short8*>(kr);
        short8 kf1 = *reinterpret_cast<const short8*>(kr + 16);
        s[jt] = MFMA32(kf0, qf0, s[jt]);
        s[jt] = MFMA32(kf1, qf1, s[jt]);
      }
      // P = exp2(S') in place
#pragma unroll
      for (int jt = 0; jt < 4; ++jt)
#pragma unroll
        for (int r = 0; r < 16; ++r) s[jt][r] = __builtin_amdgcn_exp2f(s[jt][r]);
      // pack pairs: pk[jt][m][h2] = bf16x2 of P at j = 32jt + 8m + 4hi + 2h2 + {0,1}
      unsigned pk[4][4][2];
#pragma unroll
      for (int jt = 0; jt < 4; ++jt)
#pragma unroll
        for (int m = 0; m < 4; ++m) {
          pk[jt][m][0] = cvtpk(s[jt][4 * m + 0], s[jt][4 * m + 1]);
          pk[jt][m][1] = cvtpk(s[jt][4 * m + 2], s[jt][4 * m + 3]);
        }
      // PV + row-sum: 8 k-steps of 16
#pragma unroll
      for (int ks = 0; ks < 8; ++ks) {
        int jt = ks >> 1, mb = 2 * (ks & 1);
        unsigned a0 = pk[jt][mb][0],     a1 = pk[jt][mb][1];
        unsigned b0 = pk[jt][mb + 1][0], b1 = pk[jt][mb + 1][1];
        pl32swap(a0, b0);                    // (a0,b0) -> (w0, w2)
        pl32swap(a1, b1);                    // (a1,b1) -> (w1, w3)
        uint4 fr = make_uint4(a0, a1, b0, b1);
        short8 pfrag = *reinterpret_cast<short8*>(&fr);
        short8 vf = *reinterpret_cast<const short8*>(&Vl[i31 * 648 + j0 + ks * 16 + hi * 8]);
        oacc = MFMA32(vf, pfrag, oacc);      // O^T[d][i]
        sacc = MFMA32(ones, pfrag, sacc);    // every reg = row sum
      }
    }
    float rc = __builtin_amdgcn_rcpf(sacc[0]);
    size_t ob = ((size_t)b * 640 + i) * 128 + h * 32;
#pragma unroll
    for (int q = 0; q < 4; ++q)
#pragma unroll
      for (int h2 = 0; h2 < 2; ++h2) {
        unsigned pr = cvtpk(oacc[4 * q + 2 * h2] * rc, oacc[4 * q + 2 * h2 + 1] * rc);
        *reinterpret_cast<unsigned*>(ows + ob + q * 8 + hi * 4 + 2 * h2) = pr;
      }
  }
}

// ---------------------------------------------------------------- out proj
// one block per (batch, 64-row tile); W_out bf16 direct from global; no LDS.
__global__ __launch_bounds__(256) void k_out(const unsigned short* __restrict__ ows,
                                             const unsigned short* __restrict__ wbf,
                                             float* __restrict__ out) {
  int blk = blockIdx.x;
  int b = blk / 10, tile = blk % 10;
  int t = threadIdx.x, w = t >> 6, lane = t & 63, r16 = lane & 15, g = lane >> 4;
  const unsigned short* Ob = ows + (size_t)b * 640 * 128;
  float* outb = out + (size_t)b * 128 * 625;
  int n0 = tile * 64;
  f32x4 acc[2][4];
#pragma unroll
  for (int mi = 0; mi < 2; ++mi)
#pragma unroll
    for (int f = 0; f < 4; ++f) acc[mi][f] = (f32x4){0.f, 0.f, 0.f, 0.f};
#pragma unroll
  for (int kk = 0; kk < 4; ++kk) {
    short8 bfr[4];
#pragma unroll
    for (int f = 0; f < 4; ++f)
      bfr[f] = *reinterpret_cast<const short8*>(Ob + (n0 + f * 16 + r16) * 128 + kk * 32 + g * 8);
#pragma unroll
    for (int mi = 0; mi < 2; ++mi) {
      short8 afr = *reinterpret_cast<const short8*>(wbf + (w * 32 + mi * 16 + r16) * 128 + kk * 32 + g * 8);
#pragma unroll
      for (int f = 0; f < 4; ++f) acc[mi][f] = MFMA16(afr, bfr[f], acc[mi][f]);
    }
  }
#pragma unroll
  for (int mi = 0; mi < 2; ++mi)
#pragma unroll
    for (int f = 0; f < 4; ++f) {
      int n = n0 + f * 16 + r16;
      if (n < 625) {
        int dout = w * 32 + mi * 16 + 4 * g;
        outb[(dout + 0) * 625 + n] = acc[mi][f][0];
        outb[(dout + 1) * 625 + n] = acc[mi][f][1];
        outb[(dout + 2) * 625 + n] = acc[mi][f][2];
        outb[(dout + 3) * 625 + n] = acc[mi][f][3];
      }
    }
}

// ---------------------------------------------------------------- launch
extern "C" void kernel_launch(void* const* d_in, const int* in_sizes, int n_in,
                              void* d_out, int out_size, void* d_ws, size_t ws_size,
                              hipStream_t stream) {
  const float* x     = (const float*)d_in[0];
  const float* wqkv  = (const float*)d_in[1];
  const float* wout  = (const float*)d_in[2];
  const float* table = (const float*)d_in[3];
  const int*   idx   = (const int*)d_in[4];
  float* out = (float*)d_out;

  char* ws = (char*)d_ws;  // requires ~192.2 MB
  unsigned short* qws   = (unsigned short*)(ws);
  unsigned short* kws   = (unsigned short*)(ws + 41943040);
  unsigned short* vtws  = (unsigned short*)(ws + 83886080);
  unsigned short* ows   = (unsigned short*)(ws + 125829120);
  unsigned short* bt    = (unsigned short*)(ws + 167772160);
  unsigned short* wq_bf = (unsigned short*)(ws + 171048960);
  unsigned short* wo_bf = (unsigned short*)(ws + 171147264);
  unsigned short* xtws  = (unsigned short*)(ws + 171180032);

  k_prep<<<dim3(256), dim3(256), 0, stream>>>(wqkv, wout, wq_bf, wo_bf);
  k_bias<<<dim3(400), dim3(256), 0, stream>>>(table, idx, bt);
  k_xpose<<<dim3(2560), dim3(256), 0, stream>>>(x, xtws);
  k_qkv<<<dim3(5120), dim3(256), 0, stream>>>(xtws, wq_bf, qws, kws, vtws);
  k_attn<<<dim3(1024), dim3(512), 0, stream>>>(qws, kws, vtws, bt, ows);
  k_out<<<dim3(2560), dim3(256), 0, stream>>>(ows, wo_bf, out);
}

// Round 8
// 276.395 us; speedup vs baseline: 1.0092x; 1.0092x over previous
//
#include <hip/hip_runtime.h>
#include <hip/hip_bf16.h>

// Attention_44006234915573 — windowed attention, MI355X/gfx950
// B=256, D=128, HEADS=4, DH=32, N=625 (padded to 640).
//
// R8 (bisect): k_attn reverted to the R6-verified version (512 thr, K+V in
// LDS, direct mapping). k_pre fusion + k_qkv + k_out kept from R7.
// If this passes at 6.103516e-05 the R7 fault is in k_attn's
// {global-K, 640-thr launch-bounds, XCD-remap} trio; if it fails, k_pre.
//
// ws layout (bytes):
//   [0,          +40M)  Q  bf16 [1024][640][32] (pre-scaled by SCALE*LOG2E)
//   [41943040,   +40M)  K  bf16 [1024][640][32]
//   [83886080,   +40M)  Vt bf16 [1024][32][640]
//   [125829120,  +40M)  O  bf16 [256][640][128] (head-major channels)
//   [167772160, +3.3M)  bias bf16 [4][160 jg][640 i][4]  (pre-x LOG2E)
//   [171048960, +96K)   W_qkv bf16 [384][128]
//   [171147264, +32K)   W_out bf16 [128][128]
//   [171180032, +20.9M) xT bf16 [256][640][128]
// total 192,152,072 bytes of d_ws.

typedef __attribute__((ext_vector_type(8)))  short short8;
typedef __attribute__((ext_vector_type(4)))  float f32x4;
typedef __attribute__((ext_vector_type(16))) float f32x16;

#define MFMA16(a, b, c) __builtin_amdgcn_mfma_f32_16x16x32_bf16((a), (b), (c), 0, 0, 0)
#define MFMA32(a, b, c) __builtin_amdgcn_mfma_f32_32x32x16_bf16((a), (b), (c), 0, 0, 0)

__device__ __forceinline__ unsigned short f2b(float f) {
  __hip_bfloat16 h = __float2bfloat16(f);
  return *reinterpret_cast<unsigned short*>(&h);
}
__device__ __forceinline__ float b2f(unsigned short s) {
  union { unsigned u; float f; } x; x.u = ((unsigned)s) << 16;
  return x.f;
}
__device__ __forceinline__ unsigned cvtpk(float lo, float hi) {
  unsigned r;
  asm("v_cvt_pk_bf16_f32 %0, %1, %2" : "=v"(r) : "v"(lo), "v"(hi));
  return r;
}
__device__ __forceinline__ void pl32swap(unsigned& a, unsigned& b) {
  asm("v_permlane32_swap_b32 %0, %1" : "+v"(a), "+v"(b));
}

constexpr float LOG2E_F = 1.4426950408889634f;
constexpr float QSCALE  = 0.17677669529663687f * 1.4426950408889634f;  // dh^-0.5 * log2(e)

// ---------------------------------------------------------------- fused pre
// blocks [0,256): W cvt; [256,656): bias expand; [656,3216): x transpose
__global__ __launch_bounds__(256) void k_pre(const float* __restrict__ wqkv,
                                             const float* __restrict__ wout,
                                             const float* __restrict__ table,
                                             const int* __restrict__ idx,
                                             const float* __restrict__ x,
                                             unsigned short* __restrict__ wq_bf,
                                             unsigned short* __restrict__ wo_bf,
                                             unsigned short* __restrict__ bt,
                                             unsigned short* __restrict__ xt) {
  __shared__ unsigned short Xl[128 * 65];    // 16.6 KB (xpose branch only)
  int blk = blockIdx.x, t = threadIdx.x;
  if (blk < 256) {
    int id = blk * 256 + t;                  // 65536 = 49152 + 16384
    if (id < 49152) wq_bf[id] = f2b(wqkv[id]);
    else            wo_bf[id - 49152] = f2b(wout[id - 49152]);
  } else if (blk < 656) {
    int id = (blk - 256) * 256 + t;          // 102400 over (jg, i)
    int jg = id / 640, i = id % 640;
    float v[4][4];                           // [e][h]
#pragma unroll
    for (int e = 0; e < 4; ++e) {
      int j = jg * 4 + e;
      if (j >= 625) {
#pragma unroll
        for (int h = 0; h < 4; ++h) v[e][h] = -1e30f;
      } else if (i >= 625) {
#pragma unroll
        for (int h = 0; h < 4; ++h) v[e][h] = 0.f;
      } else {
        const float* tr = table + idx[i * 625 + j] * 4;
#pragma unroll
        for (int h = 0; h < 4; ++h) v[e][h] = tr[h] * LOG2E_F;
      }
    }
#pragma unroll
    for (int h = 0; h < 4; ++h) {
      ushort4 p;
      p.x = f2b(v[0][h]); p.y = f2b(v[1][h]); p.z = f2b(v[2][h]); p.w = f2b(v[3][h]);
      *reinterpret_cast<ushort4*>(bt + (size_t)h * 409600 + (size_t)id * 4) = p;
    }
  } else {
    int bk = blk - 656;                      // 2560 = 256 b x 10 tile
    int b = bk / 10, tile = bk % 10;
    int n0 = tile * 64;
    const float* xb = x + (size_t)b * 80000;
    for (int it = 0; it < 32; ++it) {
      int id = it * 256 + t;                 // 8192 = 128 d x 64 n
      int d = id >> 6, nc = id & 63, n = n0 + nc;
      Xl[d * 65 + nc] = (n < 625) ? f2b(xb[d * 625 + n]) : (unsigned short)0;
    }
    __syncthreads();
    unsigned short* xtb = xt + ((size_t)b * 640 + n0) * 128;
    for (int it = 0; it < 4; ++it) {
      int id = it * 256 + t;                 // 1024 short8 chunks
      int row = id >> 4, c8 = (id & 15) * 8;
      short8 v;
#pragma unroll
      for (int jj = 0; jj < 8; ++jj) v[jj] = (short)Xl[(c8 + jj) * 65 + row];
      *reinterpret_cast<short8*>(xtb + row * 128 + c8) = v;
    }
  }
}

// ---------------------------------------------------------------- QKV proj
// LDS-free: one block per (b, 64-row tile, col-flavor); wave w owns 3 col
// fragments F0..F0+2; W in registers; A-frags = b128 loads from xT.
__global__ __launch_bounds__(256) void k_qkv(const unsigned short* __restrict__ xt,
                                             const unsigned short* __restrict__ wbf,
                                             unsigned short* __restrict__ qws,
                                             unsigned short* __restrict__ kws,
                                             unsigned short* __restrict__ vtws) {
  int blk = blockIdx.x;                      // 5120 = 256 b x 10 tile x 2 cf
  int cf = blk & 1, btl = blk >> 1;
  int b = btl / 10, tile = btl % 10;
  int t = threadIdx.x, w = t >> 6, lane = t & 63, r16 = lane & 15, g = lane >> 4;
  int F0 = cf * 12 + w * 3;
  short8 wf[3][4];
#pragma unroll
  for (int f = 0; f < 3; ++f)
#pragma unroll
    for (int kk = 0; kk < 4; ++kk)
      wf[f][kk] = *reinterpret_cast<const short8*>(
          wbf + ((F0 + f) * 16 + r16) * 128 + kk * 32 + g * 8);
  const unsigned short* xb = xt + ((size_t)b * 640 + tile * 64) * 128;
#pragma unroll
  for (int rg = 0; rg < 4; ++rg) {
    short8 a[4];
#pragma unroll
    for (int kk = 0; kk < 4; ++kk)
      a[kk] = *reinterpret_cast<const short8*>(xb + (rg * 16 + r16) * 128 + kk * 32 + g * 8);
    f32x4 acc[3];
#pragma unroll
    for (int f = 0; f < 3; ++f) acc[f] = (f32x4){0.f, 0.f, 0.f, 0.f};
#pragma unroll
    for (int kk = 0; kk < 4; ++kk)
#pragma unroll
      for (int f = 0; f < 3; ++f)
        acc[f] = MFMA16(a[kk], wf[f][kk], acc[f]);
    int nr = tile * 64 + rg * 16;
#pragma unroll
    for (int f = 0; f < 3; ++f) {
      int c0 = (F0 + f) * 16;
      int sel = c0 >> 7, hh = (c0 & 127) >> 5, t0 = (c0 & 31);
      float mul = (sel == 0) ? QSCALE : 1.f;
      size_t base = (size_t)(b * 4 + hh);
      if (sel < 2) {
        unsigned short* dst = (sel ? kws : qws) + (base * 640 + nr + 4 * g) * 32 + t0 + r16;
#pragma unroll
        for (int rr = 0; rr < 4; ++rr) dst[rr * 32] = f2b(acc[f][rr] * mul);
      } else {
        ushort4 pv;
        pv.x = f2b(acc[f][0]); pv.y = f2b(acc[f][1]);
        pv.z = f2b(acc[f][2]); pv.w = f2b(acc[f][3]);
        *reinterpret_cast<ushort4*>(vtws + (base * 32 + t0 + r16) * 640 + nr + 4 * g) = pv;
      }
    }
  }
}

// ---------------------------------------------------------------- attention
// R6-verified: one block (512 thr, 8 waves) per (b,h); K+V in LDS; swapped
// 32x32 MFMA; in-register softmax (cvt_pk + permlane32_swap); row-sums via
// MFMA with A=ones.
__global__ __launch_bounds__(512) void k_attn(const unsigned short* __restrict__ qws,
                                              const unsigned short* __restrict__ kws,
                                              const unsigned short* __restrict__ vtws,
                                              const unsigned short* __restrict__ bt,
                                              unsigned short* __restrict__ ows) {
  __shared__ __align__(16) unsigned short Kl[640 * 40];   // 51.2 KB, pitch 80B
  __shared__ __align__(16) unsigned short Vl[32 * 648];   // 41.5 KB
  int bh = blockIdx.x, b = bh >> 2, h = bh & 3;
  int t = threadIdx.x, w = t >> 6, lane = t & 63;
  int i31 = lane & 31, hi = lane >> 5;
  const unsigned short* Kg = kws + (size_t)bh * 20480;
  const unsigned short* Vg = vtws + (size_t)bh * 20480;
  for (int it = 0; it < 5; ++it) {
    int idx = it * 512 + t;                  // 2560 8-elem blocks of K
    int row = idx >> 2, c8 = (idx & 3) * 8;
    *reinterpret_cast<short8*>(&Kl[row * 40 + c8]) =
        *reinterpret_cast<const short8*>(Kg + row * 32 + c8);
  }
  for (int it = 0; it < 5; ++it) {
    int idx = it * 512 + t;                  // 2560 8-elem blocks of V
    int d = idx / 80, nb = (idx % 80) * 8;
    *reinterpret_cast<short8*>(&Vl[d * 648 + nb]) =
        *reinterpret_cast<const short8*>(Vg + d * 640 + nb);
  }
  __syncthreads();
  const unsigned short* Qg = qws + (size_t)bh * 20480;
  const unsigned short* bth = bt + (size_t)h * 409600;
  short8 ones;
#pragma unroll
  for (int jj = 0; jj < 8; ++jj) ones[jj] = (short)0x3F80;  // bf16 1.0

  for (int ti = w; ti < 20; ti += 8) {       // wave's 32-row Q tiles
    int i = ti * 32 + i31;
    short8 qf0 = *reinterpret_cast<const short8*>(Qg + i * 32 + hi * 8);
    short8 qf1 = *reinterpret_cast<const short8*>(Qg + i * 32 + 16 + hi * 8);
    f32x16 oacc, sacc;
#pragma unroll
    for (int r = 0; r < 16; ++r) { oacc[r] = 0.f; sacc[r] = 0.f; }
    for (int c = 0; c < 5; ++c) {
      int j0 = c * 128;
      f32x16 s[4];
      // bias as C-operand: s[jt][4q+e] = bias^T[j0+32jt+8q+4hi+e][i]
#pragma unroll
      for (int jt = 0; jt < 4; ++jt) {
#pragma unroll
        for (int q = 0; q < 4; ++q) {
          int jg = (j0 >> 2) + jt * 8 + q * 2 + hi;
          ushort4 bv = *reinterpret_cast<const ushort4*>(bth + ((size_t)jg * 640 + i) * 4);
          s[jt][4 * q + 0] = b2f(bv.x);
          s[jt][4 * q + 1] = b2f(bv.y);
          s[jt][4 * q + 2] = b2f(bv.z);
          s[jt][4 * q + 3] = b2f(bv.w);
        }
      }
      // S^T = K Q^T + bias  (32x32 j-tiles, k = dh = 32 in two halves)
#pragma unroll
      for (int jt = 0; jt < 4; ++jt) {
        const unsigned short* kr = &Kl[(j0 + jt * 32 + i31) * 40 + hi * 8];
        short8 kf0 = *reinterpret_cast<const short8*>(kr);
        short8 kf1 = *reinterpret_cast<const short8*>(kr + 16);
        s[jt] = MFMA32(kf0, qf0, s[jt]);
        s[jt] = MFMA32(kf1, qf1, s[jt]);
      }
      // P = exp2(S') in place
#pragma unroll
      for (int jt = 0; jt < 4; ++jt)
#pragma unroll
        for (int r = 0; r < 16; ++r) s[jt][r] = __builtin_amdgcn_exp2f(s[jt][r]);
      // pack pairs: pk[jt][m][h2] = bf16x2 of P at j = 32jt + 8m + 4hi + 2h2 + {0,1}
      unsigned pk[4][4][2];
#pragma unroll
      for (int jt = 0; jt < 4; ++jt)
#pragma unroll
        for (int m = 0; m < 4; ++m) {
          pk[jt][m][0] = cvtpk(s[jt][4 * m + 0], s[jt][4 * m + 1]);
          pk[jt][m][1] = cvtpk(s[jt][4 * m + 2], s[jt][4 * m + 3]);
        }
      // PV + row-sum: 8 k-steps of 16
#pragma unroll
      for (int ks = 0; ks < 8; ++ks) {
        int jt = ks >> 1, mb = 2 * (ks & 1);
        unsigned a0 = pk[jt][mb][0],     a1 = pk[jt][mb][1];
        unsigned b0 = pk[jt][mb + 1][0], b1 = pk[jt][mb + 1][1];
        pl32swap(a0, b0);                    // (a0,b0) -> (w0, w2)
        pl32swap(a1, b1);                    // (a1,b1) -> (w1, w3)
        uint4 fr = make_uint4(a0, a1, b0, b1);
        short8 pfrag = *reinterpret_cast<short8*>(&fr);
        short8 vf = *reinterpret_cast<const short8*>(&Vl[i31 * 648 + j0 + ks * 16 + hi * 8]);
        oacc = MFMA32(vf, pfrag, oacc);      // O^T[d][i]
        sacc = MFMA32(ones, pfrag, sacc);    // every reg = row sum
      }
    }
    float rc = __builtin_amdgcn_rcpf(sacc[0]);
    size_t ob = ((size_t)b * 640 + i) * 128 + h * 32;
#pragma unroll
    for (int q = 0; q < 4; ++q)
#pragma unroll
      for (int h2 = 0; h2 < 2; ++h2) {
        unsigned pr = cvtpk(oacc[4 * q + 2 * h2] * rc, oacc[4 * q + 2 * h2 + 1] * rc);
        *reinterpret_cast<unsigned*>(ows + ob + q * 8 + hi * 4 + 2 * h2) = pr;
      }
  }
}

// ---------------------------------------------------------------- out proj
// one block per (batch, 64-row tile); W_out bf16 direct from global; no LDS.
__global__ __launch_bounds__(256) void k_out(const unsigned short* __restrict__ ows,
                                             const unsigned short* __restrict__ wbf,
                                             float* __restrict__ out) {
  int blk = blockIdx.x;
  int b = blk / 10, tile = blk % 10;
  int t = threadIdx.x, w = t >> 6, lane = t & 63, r16 = lane & 15, g = lane >> 4;
  const unsigned short* Ob = ows + (size_t)b * 640 * 128;
  float* outb = out + (size_t)b * 128 * 625;
  int n0 = tile * 64;
  f32x4 acc[2][4];
#pragma unroll
  for (int mi = 0; mi < 2; ++mi)
#pragma unroll
    for (int f = 0; f < 4; ++f) acc[mi][f] = (f32x4){0.f, 0.f, 0.f, 0.f};
#pragma unroll
  for (int kk = 0; kk < 4; ++kk) {
    short8 bfr[4];
#pragma unroll
    for (int f = 0; f < 4; ++f)
      bfr[f] = *reinterpret_cast<const short8*>(Ob + (n0 + f * 16 + r16) * 128 + kk * 32 + g * 8);
#pragma unroll
    for (int mi = 0; mi < 2; ++mi) {
      short8 afr = *reinterpret_cast<const short8*>(wbf + (w * 32 + mi * 16 + r16) * 128 + kk * 32 + g * 8);
#pragma unroll
      for (int f = 0; f < 4; ++f) acc[mi][f] = MFMA16(afr, bfr[f], acc[mi][f]);
    }
  }
#pragma unroll
  for (int mi = 0; mi < 2; ++mi)
#pragma unroll
    for (int f = 0; f < 4; ++f) {
      int n = n0 + f * 16 + r16;
      if (n < 625) {
        int dout = w * 32 + mi * 16 + 4 * g;
        outb[(dout + 0) * 625 + n] = acc[mi][f][0];
        outb[(dout + 1) * 625 + n] = acc[mi][f][1];
        outb[(dout + 2) * 625 + n] = acc[mi][f][2];
        outb[(dout + 3) * 625 + n] = acc[mi][f][3];
      }
    }
}

// ---------------------------------------------------------------- launch
extern "C" void kernel_launch(void* const* d_in, const int* in_sizes, int n_in,
                              void* d_out, int out_size, void* d_ws, size_t ws_size,
                              hipStream_t stream) {
  const float* x     = (const float*)d_in[0];
  const float* wqkv  = (const float*)d_in[1];
  const float* wout  = (const float*)d_in[2];
  const float* table = (const float*)d_in[3];
  const int*   idx   = (const int*)d_in[4];
  float* out = (float*)d_out;

  char* ws = (char*)d_ws;  // requires ~192.2 MB
  unsigned short* qws   = (unsigned short*)(ws);
  unsigned short* kws   = (unsigned short*)(ws + 41943040);
  unsigned short* vtws  = (unsigned short*)(ws + 83886080);
  unsigned short* ows   = (unsigned short*)(ws + 125829120);
  unsigned short* bt    = (unsigned short*)(ws + 167772160);
  unsigned short* wq_bf = (unsigned short*)(ws + 171048960);
  unsigned short* wo_bf = (unsigned short*)(ws + 171147264);
  unsigned short* xtws  = (unsigned short*)(ws + 171180032);

  k_pre<<<dim3(3216), dim3(256), 0, stream>>>(wqkv, wout, table, idx, x,
                                              wq_bf, wo_bf, bt, xtws);
  k_qkv<<<dim3(5120), dim3(256), 0, stream>>>(xtws, wq_bf, qws, kws, vtws);
  k_attn<<<dim3(1024), dim3(512), 0, stream>>>(qws, kws, vtws, bt, ows);
  k_out<<<dim3(2560), dim3(256), 0, stream>>>(ows, wo_bf, out);
}